// Round 2
// baseline (119.140 us; speedup 1.0000x reference)
//
#include <hip/hip_runtime.h>

// Problem constants (from reference): B=1048576, M=8, K=3, R=8
#define M_N 8
#define K_N 3
#define R_N 8
// Per-rule packed params in d_ws: [cc[8] | inv_sigma[8] | cons[9] | pad..] = 32 floats
#define RULE_STRIDE 32

// One-block pre-kernel: gather c / inv_sigma through rules, copy consequents.
__global__ void anfis_precompute(const float* __restrict__ c,
                                 const float* __restrict__ log_sigma,
                                 const float* __restrict__ consequents,
                                 const int* __restrict__ rules,
                                 float* __restrict__ params) {
    int tid = threadIdx.x;
    if (tid < R_N * M_N) {                       // 64 threads: cc + inv_sigma
        int r = tid >> 3, m = tid & 7;
        int k = rules[r * M_N + m];
        float sig = expf(log_sigma[m * K_N + k]) + 1e-6f;
        params[r * RULE_STRIDE + m]       = c[m * K_N + k];
        params[r * RULE_STRIDE + 8 + m]   = 1.0f / sig;
    }
    if (tid < R_N * (M_N + 1)) {                 // 72 threads: consequents (R x 9)
        int r = tid / 9, j = tid - r * 9;
        params[r * RULE_STRIDE + 16 + j] = consequents[r * (M_N + 1) + j];
    }
}

// Lane layout: within each 64-lane wave, lane = e*8 + r  (e = element-in-group,
// r = rule). Each lane holds ONE rule's params in 28 VGPRs, loaded once and
// reused across a grid-stride loop -> no per-element param reloads.
// Firing-sum / y-sum are 3-step shfl_xor reductions inside 8-lane clusters.
__global__ __launch_bounds__(256) void anfis_main(
        const float* __restrict__ x,
        const float* __restrict__ params,
        float* __restrict__ out,
        int B) {
    const int lane = threadIdx.x & 63;
    const int r    = lane & 7;       // rule owned by this lane
    const int e    = lane >> 3;      // element slot within the wave's group of 8
    const int wave   = (blockIdx.x * blockDim.x + threadIdx.x) >> 6;
    const int nwaves = (gridDim.x * blockDim.x) >> 6;

    // Per-lane rule params: 7 float4 broadcast loads, live in VGPRs for the loop.
    const float4* pp = (const float4*)(params + r * RULE_STRIDE);
    const float4 cc0 = pp[0], cc1 = pp[1];   // centers (gathered)
    const float4 is0 = pp[2], is1 = pp[3];   // 1/sigma
    const float4 co0 = pp[4], co1 = pp[5];   // cons[0..3], cons[4..7]
    const float  co8 = params[r * RULE_STRIDE + 24];  // cons[8]

    const int ngroups = B >> 3;   // B divisible by 8 for this problem (1048576)
    for (int g = wave; g < ngroups; g += nwaves) {
        const int b = (g << 3) + e;

        const float4* xp = (const float4*)(x + (size_t)b * M_N);
        const float4 x0 = xp[0];
        const float4 x1 = xp[1];

        // s = sum_m ((x_m - c_m)/sigma_m)^2   (firing = exp(-0.5 s))
        float t, s = 0.0f;
        t = (x0.x - cc0.x) * is0.x; s = fmaf(t, t, s);
        t = (x0.y - cc0.y) * is0.y; s = fmaf(t, t, s);
        t = (x0.z - cc0.z) * is0.z; s = fmaf(t, t, s);
        t = (x0.w - cc0.w) * is0.w; s = fmaf(t, t, s);
        t = (x1.x - cc1.x) * is1.x; s = fmaf(t, t, s);
        t = (x1.y - cc1.y) * is1.y; s = fmaf(t, t, s);
        t = (x1.z - cc1.z) * is1.z; s = fmaf(t, t, s);
        t = (x1.w - cc1.w) * is1.w; s = fmaf(t, t, s);

        // y_r = cons[0] + sum_m cons[m+1] * x_m
        float acc = co0.x;
        acc = fmaf(co0.y, x0.x, acc);
        acc = fmaf(co0.z, x0.y, acc);
        acc = fmaf(co0.w, x0.z, acc);
        acc = fmaf(co1.x, x0.w, acc);
        acc = fmaf(co1.y, x1.x, acc);
        acc = fmaf(co1.z, x1.y, acc);
        acc = fmaf(co1.w, x1.z, acc);
        acc = fmaf(co8,  x1.w, acc);

        const float fir = __expf(-0.5f * s);

        // firing sum across the 8 rules of this element (8-lane cluster)
        float fsum = fir;
        fsum += __shfl_xor(fsum, 1, 8);
        fsum += __shfl_xor(fsum, 2, 8);
        fsum += __shfl_xor(fsum, 4, 8);

        const float wn = fir * __builtin_amdgcn_rcpf(fsum + 1e-8f);

        // y = sum_r wn * y_r
        float p = wn * acc;
        p += __shfl_xor(p, 1, 8);
        p += __shfl_xor(p, 2, 8);
        p += __shfl_xor(p, 4, 8);

        // Outputs: y[B] | w_norm[B*R] | y_r[B*R]
        // w_norm/y_r flat index = b*8 + r = g*64 + lane  -> perfectly coalesced.
        float* wbase = out + (size_t)B + ((size_t)g << 6);
        __builtin_nontemporal_store(wn, wbase + lane);
        float* ybase = out + (size_t)B * 9 + ((size_t)g << 6);
        __builtin_nontemporal_store(acc, ybase + lane);
        if (r == 0) __builtin_nontemporal_store(p, out + b);
    }
}

extern "C" void kernel_launch(void* const* d_in, const int* in_sizes, int n_in,
                              void* d_out, int out_size, void* d_ws, size_t ws_size,
                              hipStream_t stream) {
    const float* x           = (const float*)d_in[0];
    const float* c           = (const float*)d_in[1];
    const float* log_sigma   = (const float*)d_in[2];
    const float* consequents = (const float*)d_in[3];
    const int*   rules       = (const int*)d_in[4];
    float* out = (float*)d_out;
    float* params = (float*)d_ws;   // R_N * RULE_STRIDE floats = 1 KB

    int B = in_sizes[0] / M_N;

    anfis_precompute<<<1, 128, 0, stream>>>(c, log_sigma, consequents, rules, params);
    // 2048 blocks * 4 waves = 8192 waves (32/CU capacity); 16 grid-stride iters.
    anfis_main<<<2048, 256, 0, stream>>>(x, params, out, B);
}

// Round 3
// 109.794 us; speedup vs baseline: 1.0851x; 1.0851x over previous
//
#include <hip/hip_runtime.h>

// Problem constants (from reference): B=1048576, M=8, K=3, R=8
#define M_N 8
#define K_N 3
#define R_N 8
// Per-rule packed params in d_ws: [cc[8] | inv_sigma[8] | cons[9] | pad..] = 32 floats
#define RULE_STRIDE 32

// One-block pre-kernel: gather c / inv_sigma through rules, copy consequents.
__global__ void anfis_precompute(const float* __restrict__ c,
                                 const float* __restrict__ log_sigma,
                                 const float* __restrict__ consequents,
                                 const int* __restrict__ rules,
                                 float* __restrict__ params) {
    int tid = threadIdx.x;
    if (tid < R_N * M_N) {                       // 64 threads: cc + inv_sigma
        int r = tid >> 3, m = tid & 7;
        int k = rules[r * M_N + m];
        float sig = expf(log_sigma[m * K_N + k]) + 1e-6f;
        params[r * RULE_STRIDE + m]       = c[m * K_N + k];
        params[r * RULE_STRIDE + 8 + m]   = 1.0f / sig;
    }
    if (tid < R_N * (M_N + 1)) {                 // 72 threads: consequents (R x 9)
        int r = tid / 9, j = tid - r * 9;
        params[r * RULE_STRIDE + 16 + j] = consequents[r * (M_N + 1) + j];
    }
}

// One thread per element. params is a wave-uniform pointer with compile-time
// offsets -> compiler emits s_load (scalar cache), amortized across the wave.
// All global loads/stores are fully coalesced (float4 where possible).
__global__ __launch_bounds__(256) void anfis_main(
        const float* __restrict__ x,
        const float* __restrict__ params,
        float* __restrict__ out,
        int B) {
    int b = blockIdx.x * blockDim.x + threadIdx.x;
    if (b >= B) return;

    const float4* xp = (const float4*)(x + (size_t)b * M_N);
    float4 x0 = xp[0];
    float4 x1 = xp[1];
    float xv[M_N] = {x0.x, x0.y, x0.z, x0.w, x1.x, x1.y, x1.z, x1.w};

    float fir[R_N], yr[R_N];
    float fsum = 0.0f;
#pragma unroll
    for (int r = 0; r < R_N; ++r) {
        const float* p = params + r * RULE_STRIDE;  // s_load offsets
        float s = 0.0f;
        float acc = p[16];                           // bias
#pragma unroll
        for (int m = 0; m < M_N; ++m) {
            float t = (xv[m] - p[m]) * p[8 + m];
            s   = fmaf(t, t, s);
            acc = fmaf(p[17 + m], xv[m], acc);
        }
        // prod_m exp(-0.5 t^2) == exp(-0.5 * sum t^2)
        fir[r] = __expf(-0.5f * s);
        yr[r]  = acc;
        fsum  += fir[r];
    }

    float inv = __builtin_amdgcn_rcpf(fsum + 1e-8f);  // passed absmax in R2
    float wn[R_N];
    float y = 0.0f;
#pragma unroll
    for (int r = 0; r < R_N; ++r) {
        wn[r] = fir[r] * inv;
        y = fmaf(wn[r], yr[r], y);
    }

    // Outputs concatenated: y[B] | w_norm[B*R] | y_r[B*R]
    out[b] = y;
    float4* wout = (float4*)(out + (size_t)B + (size_t)b * R_N);
    wout[0] = make_float4(wn[0], wn[1], wn[2], wn[3]);
    wout[1] = make_float4(wn[4], wn[5], wn[6], wn[7]);
    float4* yout = (float4*)(out + (size_t)B * (1 + R_N) + (size_t)b * R_N);
    yout[0] = make_float4(yr[0], yr[1], yr[2], yr[3]);
    yout[1] = make_float4(yr[4], yr[5], yr[6], yr[7]);
}

extern "C" void kernel_launch(void* const* d_in, const int* in_sizes, int n_in,
                              void* d_out, int out_size, void* d_ws, size_t ws_size,
                              hipStream_t stream) {
    const float* x           = (const float*)d_in[0];
    const float* c           = (const float*)d_in[1];
    const float* log_sigma   = (const float*)d_in[2];
    const float* consequents = (const float*)d_in[3];
    const int*   rules       = (const int*)d_in[4];
    float* out = (float*)d_out;
    float* params = (float*)d_ws;   // R_N * RULE_STRIDE floats = 1 KB

    int B = in_sizes[0] / M_N;

    anfis_precompute<<<1, 128, 0, stream>>>(c, log_sigma, consequents, rules, params);
    anfis_main<<<(B + 255) / 256, 256, 0, stream>>>(x, params, out, B);
}